// Round 1
// baseline (259.775 us; speedup 1.0000x reference)
//
#include <hip/hip_runtime.h>
#include <hip/hip_bf16.h>
#include <stdint.h>

// ---------------------------------------------------------------------------
// BNNLinear: out = BatchNorm( sign(x) @ sign(W)^T )
//   x: [M, K] f32, W: [N, K] f32, gamma/beta: [N] f32  ->  out: [M, N] f32
// M=8192, N=2048, K=2048 (derived from in_sizes at runtime).
//
// Pipeline:
//   1) binarize x -> bf16 {-1,0,+1} in ws (A), W -> bf16 in ws (B)
//   2) bf16 MFMA GEMM (m97 recipe: 128x128 tile, BK=32, global_load_lds w=16)
//      -> C fp32 into d_out; epilogue accumulates per-column sum/sumsq
//      (integer-exact in fp32) via shuffle-reduce + global atomics
//   3) finalize per-column scale/shift
//   4) in-place normalize d_out
// ---------------------------------------------------------------------------

typedef __bf16 bf16x8 __attribute__((ext_vector_type(8)));
typedef float f32x4 __attribute__((ext_vector_type(4)));

#define BM 128
#define BN 128
#define BK 32
#define EPS_BN 1e-5f

__device__ __forceinline__ void load16_lds(const void* g, void* l) {
  // 16B per lane, dest = wave-uniform base + lane*16
  __builtin_amdgcn_global_load_lds(
      (const __attribute__((address_space(1))) void*)g,
      (__attribute__((address_space(3))) void*)l,
      16, 0, 0);
}

// ---- 1) binarize f32 -> bf16 sign bits (as ushort) ------------------------
__global__ void binarize_kernel(const float* __restrict__ in,
                                ushort* __restrict__ out, int n4) {
  int idx = blockIdx.x * blockDim.x + threadIdx.x;
  if (idx >= n4) return;
  const float4 v = reinterpret_cast<const float4*>(in)[idx];
  ushort4 o;
  o.x = v.x > 0.f ? 0x3F80 : (v.x < 0.f ? 0xBF80 : 0);
  o.y = v.y > 0.f ? 0x3F80 : (v.y < 0.f ? 0xBF80 : 0);
  o.z = v.z > 0.f ? 0x3F80 : (v.z < 0.f ? 0xBF80 : 0);
  o.w = v.w > 0.f ? 0x3F80 : (v.w < 0.f ? 0xBF80 : 0);
  reinterpret_cast<ushort4*>(out)[idx] = o;
}

// ---- 2) GEMM: C[i][j] = sum_k A[i][k] * Bt[j][k] --------------------------
__global__ __launch_bounds__(256) void gemm_bt_kernel(
    const ushort* __restrict__ A,   // [M][K] bf16 bits
    const ushort* __restrict__ Bt,  // [N][K] bf16 bits
    float* __restrict__ C,          // [M][N]
    float* __restrict__ colSum,     // [N] (pre-zeroed)
    float* __restrict__ colSq,      // [N] (pre-zeroed)
    int M, int N, int K) {
  __shared__ __align__(16) ushort sA[BM * BK];
  __shared__ __align__(16) ushort sB[BN * BK];

  const int tid  = threadIdx.x;
  const int wave = tid >> 6;
  const int lane = tid & 63;

  const int rowBlock = blockIdx.y * BM;
  const int colBlock = blockIdx.x * BN;

  // staging: each wave stages 32 rows of A and 32 rows of B (2 calls each,
  // 16 rows per global_load_lds: 64 lanes x 16B = 16 rows x 64B)
  const int laneRow = lane >> 2;       // 0..15
  const int laneCol = (lane & 3) * 8;  // bf16-element offset: 0,8,16,24

  const ushort* Ag = A  + (size_t)(rowBlock + wave * 32 + laneRow) * K + laneCol;
  const ushort* Bg = Bt + (size_t)(colBlock + wave * 32 + laneRow) * K + laneCol;
  ushort* sAw = &sA[(wave * 32) * BK];
  ushort* sBw = &sB[(wave * 32) * BK];

  const int fragRow = lane & 15;  // m (A) / n (B) index
  const int quad    = lane >> 4;  // k-chunk selector

  const int wr = (wave >> 1) * 64;  // wave sub-tile row offset
  const int wc = (wave & 1) * 64;   // wave sub-tile col offset

  f32x4 acc[4][4] = {};

  for (int k0 = 0; k0 < K; k0 += BK) {
    __syncthreads();  // previous iter's ds_reads done before overwrite
    load16_lds(Ag + k0,                 sAw);
    load16_lds(Ag + k0 + 16 * (size_t)K, sAw + 16 * BK);
    load16_lds(Bg + k0,                 sBw);
    load16_lds(Bg + k0 + 16 * (size_t)K, sBw + 16 * BK);
    __syncthreads();  // compiler emits vmcnt(0) drain -> staging complete

    bf16x8 af[4], bfr[4];
#pragma unroll
    for (int mi = 0; mi < 4; ++mi)
      af[mi] = *reinterpret_cast<const bf16x8*>(
          &sA[(wr + mi * 16 + fragRow) * BK + quad * 8]);
#pragma unroll
    for (int ni = 0; ni < 4; ++ni)
      bfr[ni] = *reinterpret_cast<const bf16x8*>(
          &sB[(wc + ni * 16 + fragRow) * BK + quad * 8]);
#pragma unroll
    for (int mi = 0; mi < 4; ++mi)
#pragma unroll
      for (int ni = 0; ni < 4; ++ni)
        acc[mi][ni] = __builtin_amdgcn_mfma_f32_16x16x32_bf16(
            af[mi], bfr[ni], acc[mi][ni], 0, 0, 0);
  }

  // epilogue: C/D layout col = lane&15, row = quad*4 + reg (m89-verified)
#pragma unroll
  for (int ni = 0; ni < 4; ++ni) {
    const int col = colBlock + wc + ni * 16 + fragRow;
    float s = 0.f, sq = 0.f;
#pragma unroll
    for (int mi = 0; mi < 4; ++mi) {
      const int row0 = rowBlock + wr + mi * 16 + quad * 4;
      float* Cp = C + (size_t)row0 * N + col;
#pragma unroll
      for (int r = 0; r < 4; ++r) {
        float v = acc[mi][ni][r];
        Cp[(size_t)r * N] = v;
        s += v;
        sq += v * v;
      }
    }
    // reduce over the 4 quads (rows) -> per-column partials for this wave
    s  += __shfl_xor(s, 16);  s  += __shfl_xor(s, 32);
    sq += __shfl_xor(sq, 16); sq += __shfl_xor(sq, 32);
    if (quad == 0) {
      atomicAdd(&colSum[col], s);   // integer-valued: exact in fp32
      atomicAdd(&colSq[col], sq);
    }
  }
}

// ---- 3) finalize per-column scale/shift -----------------------------------
__global__ void finalize_stats_kernel(const float* __restrict__ colSum,
                                      const float* __restrict__ colSq,
                                      const float* __restrict__ gamma,
                                      const float* __restrict__ beta,
                                      float* __restrict__ scale,
                                      float* __restrict__ shift,
                                      int N, float invM) {
  int j = blockIdx.x * blockDim.x + threadIdx.x;
  if (j >= N) return;
  float mean = colSum[j] * invM;
  float var  = colSq[j] * invM - mean * mean;  // biased, matches jnp.var
  float sc   = gamma[j] * rsqrtf(var + EPS_BN);
  scale[j] = sc;
  shift[j] = beta[j] - mean * sc;
}

// ---- 4) in-place normalize ------------------------------------------------
__global__ void normalize_kernel(float* __restrict__ C,
                                 const float* __restrict__ scale,
                                 const float* __restrict__ shift,
                                 int n4, int ncol4) {
  int idx = blockIdx.x * blockDim.x + threadIdx.x;
  if (idx >= n4) return;
  int c4 = idx % ncol4;  // 4 consecutive columns per float4 (N % 4 == 0)
  float4 v  = reinterpret_cast<float4*>(C)[idx];
  float4 sc = reinterpret_cast<const float4*>(scale)[c4];
  float4 sh = reinterpret_cast<const float4*>(shift)[c4];
  v.x = v.x * sc.x + sh.x;
  v.y = v.y * sc.y + sh.y;
  v.z = v.z * sc.z + sh.z;
  v.w = v.w * sc.w + sh.w;
  reinterpret_cast<float4*>(C)[idx] = v;
}

// ---------------------------------------------------------------------------
extern "C" void kernel_launch(void* const* d_in, const int* in_sizes, int n_in,
                              void* d_out, int out_size, void* d_ws,
                              size_t ws_size, hipStream_t stream) {
  const float* x     = (const float*)d_in[0];
  const float* w     = (const float*)d_in[1];
  const float* gamma = (const float*)d_in[2];
  const float* beta  = (const float*)d_in[3];
  float* C = (float*)d_out;

  const int N = in_sizes[2];            // OUT
  const int K = in_sizes[1] / N;        // IN
  const int M = in_sizes[0] / K;        // batch

  // workspace layout: [A bf16 M*K][B bf16 N*K][colSum N][colSq N][scale N][shift N]
  char* ws = (char*)d_ws;
  ushort* Abin = (ushort*)ws;
  ushort* Bbin = (ushort*)(ws + (size_t)M * K * sizeof(ushort));
  float* stats = (float*)(ws + (size_t)M * K * sizeof(ushort) +
                          (size_t)N * K * sizeof(ushort));
  float* colSum = stats;
  float* colSq  = stats + N;
  float* scaleB = stats + 2 * N;
  float* shiftB = stats + 3 * N;

  hipMemsetAsync(colSum, 0, 2 * (size_t)N * sizeof(float), stream);

  {
    int n4 = (M * K) / 4;
    binarize_kernel<<<(n4 + 255) / 256, 256, 0, stream>>>(x, Abin, n4);
  }
  {
    int n4 = (N * K) / 4;
    binarize_kernel<<<(n4 + 255) / 256, 256, 0, stream>>>(w, Bbin, n4);
  }

  dim3 grid(N / BN, M / BM);
  gemm_bt_kernel<<<grid, 256, 0, stream>>>(Abin, Bbin, C, colSum, colSq, M, N, K);

  finalize_stats_kernel<<<(N + 255) / 256, 256, 0, stream>>>(
      colSum, colSq, gamma, beta, scaleB, shiftB, N, 1.0f / (float)M);

  {
    int n4 = (M * N) / 4;
    normalize_kernel<<<(n4 + 255) / 256, 256, 0, stream>>>(C, scaleB, shiftB,
                                                           n4, N / 4);
  }
}

// Round 2
// 202.763 us; speedup vs baseline: 1.2812x; 1.2812x over previous
//
#include <hip/hip_runtime.h>
#include <hip/hip_bf16.h>
#include <stdint.h>

// ---------------------------------------------------------------------------
// BNNLinear: out = BatchNorm( sign(x) @ sign(W)^T )
//   x: [M, K] f32, W: [N, K] f32, gamma/beta: [N] f32  ->  out: [M, N] f32
//
// Round 2: GEMM over int8 {-1,0,+1} with v_mfma_i32_16x16x64_i8 (exact,
// 2x bf16 rate, 2x K per instruction). BK=64 (same 16 KiB LDS as round 1's
// bf16 BK=32, half the barriers/staging instrs per K). Single fused binarize
// launch; normalize uses 2D grid (no integer mod).
//
// Pipeline:
//   1) binarize x -> i8 (ws A), W -> i8 (ws B)        [one launch]
//   2) i8 MFMA GEMM -> C fp32 in d_out; epilogue accumulates per-column
//      sum/sumsq (integer-exact) via shuffle + global atomics
//   3) finalize per-column scale/shift
//   4) in-place normalize d_out
// ---------------------------------------------------------------------------

typedef int int32x4 __attribute__((ext_vector_type(4)));

#define BM 128
#define BN 128
#define BKI 64
#define EPS_BN 1e-5f

__device__ __forceinline__ void load16_lds(const void* g, void* l) {
  // 16B per lane, LDS dest = wave-uniform base + lane*16
  __builtin_amdgcn_global_load_lds(
      (const __attribute__((address_space(1))) void*)g,
      (__attribute__((address_space(3))) void*)l,
      16, 0, 0);
}

// ---- 1) binarize f32 -> i8 sign, both tensors in one launch ---------------
__global__ void binarize_kernel(const float* __restrict__ x,
                                const float* __restrict__ w,
                                char* __restrict__ Ab, char* __restrict__ Bb,
                                int nx4, int ntot4) {
  int idx = blockIdx.x * blockDim.x + threadIdx.x;
  if (idx >= ntot4) return;
  const float4* src;
  char* dst;
  int i;
  if (idx < nx4) {
    src = reinterpret_cast<const float4*>(x); dst = Ab; i = idx;
  } else {
    src = reinterpret_cast<const float4*>(w); dst = Bb; i = idx - nx4;
  }
  float4 v = src[i];
  char4 o;
  o.x = v.x > 0.f ? 1 : (v.x < 0.f ? -1 : 0);
  o.y = v.y > 0.f ? 1 : (v.y < 0.f ? -1 : 0);
  o.z = v.z > 0.f ? 1 : (v.z < 0.f ? -1 : 0);
  o.w = v.w > 0.f ? 1 : (v.w < 0.f ? -1 : 0);
  reinterpret_cast<char4*>(dst)[i] = o;
}

// ---- 2) GEMM: C[i][j] = sum_k A[i][k] * Bt[j][k] (i8 -> i32 exact) --------
__global__ __launch_bounds__(256) void gemm_i8_kernel(
    const char* __restrict__ A,   // [M][K] i8
    const char* __restrict__ Bt,  // [N][K] i8
    float* __restrict__ C,        // [M][N]
    float* __restrict__ colSum,   // [N] (pre-zeroed)
    float* __restrict__ colSq,    // [N] (pre-zeroed)
    int M, int N, int K) {
  __shared__ __align__(16) char sA[BM * BKI];  // 8 KiB
  __shared__ __align__(16) char sB[BN * BKI];  // 8 KiB

  const int tid  = threadIdx.x;
  const int wave = tid >> 6;
  const int lane = tid & 63;

  // flat-id remap: dispatch-consecutive blocks share bx (same B panel) so
  // each XCD's L2 keeps one 0.5 MB B panel hot across 64 blocks
  const int id  = blockIdx.y * gridDim.x + blockIdx.x;
  const int nby = M / BM;
  const int bx  = id / nby;
  const int by  = id % nby;
  const int rowBlock = by * BM;
  const int colBlock = bx * BN;

  // staging: per wave 32 rows of A + 32 rows of B, 2 calls each
  // (one call = 64 lanes x 16B = 16 rows x 64B)
  const int laneRow   = lane >> 2;        // 0..15
  const int laneChunk = (lane & 3) * 16;  // byte offset within 64B row

  const char* Ag = A  + (size_t)(rowBlock + wave * 32 + laneRow) * K + laneChunk;
  const char* Bg = Bt + (size_t)(colBlock + wave * 32 + laneRow) * K + laneChunk;
  char* sAw = &sA[(wave * 32) * BKI];
  char* sBw = &sB[(wave * 32) * BKI];

  const int f    = lane & 15;  // m (A) / n (B) index
  const int quad = lane >> 4;  // k-group selector (16 i8 elems each)

  const int wr = (wave >> 1) * 64;  // wave sub-tile row offset
  const int wc = (wave & 1) * 64;   // wave sub-tile col offset

  int32x4 acc[4][4] = {};

  for (int k0 = 0; k0 < K; k0 += BKI) {
    __syncthreads();  // prior ds_reads complete before overwrite
    load16_lds(Ag + k0,                  sAw);
    load16_lds(Ag + k0 + 16 * (size_t)K, sAw + 16 * BKI);
    load16_lds(Bg + k0,                  sBw);
    load16_lds(Bg + k0 + 16 * (size_t)K, sBw + 16 * BKI);
    __syncthreads();  // vmcnt drain -> staging visible

    int32x4 af[4], bfr[4];
#pragma unroll
    for (int mi = 0; mi < 4; ++mi)
      af[mi] = *reinterpret_cast<const int32x4*>(
          &sA[(wr + mi * 16 + f) * BKI + quad * 16]);
#pragma unroll
    for (int ni = 0; ni < 4; ++ni)
      bfr[ni] = *reinterpret_cast<const int32x4*>(
          &sB[(wc + ni * 16 + f) * BKI + quad * 16]);
#pragma unroll
    for (int mi = 0; mi < 4; ++mi)
#pragma unroll
      for (int ni = 0; ni < 4; ++ni)
        acc[mi][ni] = __builtin_amdgcn_mfma_i32_16x16x64_i8(
            af[mi], bfr[ni], acc[mi][ni], 0, 0, 0);
  }

  // epilogue: C/D layout col = lane&15, row = quad*4 + reg (dtype-independent,
  // m121/m123-verified incl. i8). ints |v| <= 2048 exact in fp32.
#pragma unroll
  for (int ni = 0; ni < 4; ++ni) {
    const int col = colBlock + wc + ni * 16 + f;
    float s = 0.f, sq = 0.f;
#pragma unroll
    for (int mi = 0; mi < 4; ++mi) {
      const int row0 = rowBlock + wr + mi * 16 + quad * 4;
      float* Cp = C + (size_t)row0 * N + col;
#pragma unroll
      for (int r = 0; r < 4; ++r) {
        float v = (float)acc[mi][ni][r];
        Cp[(size_t)r * N] = v;
        s += v;
        sq += v * v;
      }
    }
    s  += __shfl_xor(s, 16);  s  += __shfl_xor(s, 32);
    sq += __shfl_xor(sq, 16); sq += __shfl_xor(sq, 32);
    if (quad == 0) {
      atomicAdd(&colSum[col], s);   // integer-valued: exact in fp32
      atomicAdd(&colSq[col], sq);
    }
  }
}

// ---- 3) finalize per-column scale/shift -----------------------------------
__global__ void finalize_stats_kernel(const float* __restrict__ colSum,
                                      const float* __restrict__ colSq,
                                      const float* __restrict__ gamma,
                                      const float* __restrict__ beta,
                                      float* __restrict__ scale,
                                      float* __restrict__ shift,
                                      int N, float invM) {
  int j = blockIdx.x * blockDim.x + threadIdx.x;
  if (j >= N) return;
  float mean = colSum[j] * invM;
  float var  = colSq[j] * invM - mean * mean;  // biased, matches jnp.var
  float sc   = gamma[j] * rsqrtf(var + EPS_BN);
  scale[j] = sc;
  shift[j] = beta[j] - mean * sc;
}

// ---- 4) in-place normalize (2D grid: no integer mod) ----------------------
__global__ void normalize_kernel(float* __restrict__ C,
                                 const float* __restrict__ scale,
                                 const float* __restrict__ shift, int ncol4) {
  int c4 = blockIdx.x * blockDim.x + threadIdx.x;
  if (c4 >= ncol4) return;
  size_t row = blockIdx.y;
  float4 v  = reinterpret_cast<float4*>(C)[row * ncol4 + c4];
  float4 sc = reinterpret_cast<const float4*>(scale)[c4];
  float4 sh = reinterpret_cast<const float4*>(shift)[c4];
  v.x = v.x * sc.x + sh.x;
  v.y = v.y * sc.y + sh.y;
  v.z = v.z * sc.z + sh.z;
  v.w = v.w * sc.w + sh.w;
  reinterpret_cast<float4*>(C)[row * ncol4 + c4] = v;
}

// ---------------------------------------------------------------------------
extern "C" void kernel_launch(void* const* d_in, const int* in_sizes, int n_in,
                              void* d_out, int out_size, void* d_ws,
                              size_t ws_size, hipStream_t stream) {
  const float* x     = (const float*)d_in[0];
  const float* w     = (const float*)d_in[1];
  const float* gamma = (const float*)d_in[2];
  const float* beta  = (const float*)d_in[3];
  float* C = (float*)d_out;

  const int N = in_sizes[2];      // OUT
  const int K = in_sizes[1] / N;  // IN
  const int M = in_sizes[0] / K;  // batch

  // workspace: [A i8 M*K][B i8 N*K][colSum N][colSq N][scale N][shift N]
  char* ws = (char*)d_ws;
  char* Abin = ws;
  char* Bbin = ws + (size_t)M * K;
  float* stats = (float*)(ws + (size_t)M * K + (size_t)N * K);
  float* colSum = stats;
  float* colSq  = stats + N;
  float* scaleB = stats + 2 * N;
  float* shiftB = stats + 3 * N;

  hipMemsetAsync(colSum, 0, 2 * (size_t)N * sizeof(float), stream);

  {
    int nx4 = (M * K) / 4;
    int ntot4 = (M * K + N * K) / 4;
    binarize_kernel<<<(ntot4 + 255) / 256, 256, 0, stream>>>(x, w, Abin, Bbin,
                                                             nx4, ntot4);
  }

  dim3 grid(N / BN, M / BM);
  gemm_i8_kernel<<<grid, 256, 0, stream>>>(Abin, Bbin, C, colSum, colSq, M, N, K);

  finalize_stats_kernel<<<(N + 255) / 256, 256, 0, stream>>>(
      colSum, colSq, gamma, beta, scaleB, shiftB, N, 1.0f / (float)M);

  {
    dim3 ngrid((N / 4 + 255) / 256, M);
    normalize_kernel<<<ngrid, 256, 0, stream>>>(C, scaleB, shiftB, N / 4);
  }
}